// Round 1
// baseline (786.624 us; speedup 1.0000x reference)
//
#include <hip/hip_runtime.h>

#define DEV __device__ __forceinline__

// ---------------- workspace layout (float offsets), total 10,078,848 floats = 40.3 MB ----
#define W_PHI1L 0u          // 256*4*96*32
#define W_PHI1C 3145728u    // 1024*3*32*32
#define W_LY    6291456u    // 32*256*16
#define W_CY    6422528u    // 32*1024*16
#define W_SCL   6946816u    // 256
#define W_SHL   6947072u    // 256
#define W_SCC   6947328u    // 1024
#define W_SHC   6948352u    // 1024
#define W_PHI2L 6949376u    // 64*20*32*32
#define W_PHI2C 8260096u    // 64*16*40*32
#define W_LO2   9570816u    // 32*64*16
#define W_CO2   9603584u    // 32*64*16
#define W_SC2   9636352u    // 64
#define W_SH2   9636416u    // 64
#define W_PHI3L 9636480u    // 16*4*64*32
#define W_PHI3C 9767552u    // 16*32*8*32
#define W_LO3   9898624u    // 32*16*16
#define W_CO3   9906816u    // 32*16*16
#define W_PHIF  9915008u    // 16*64*32
#define W_MF    9947776u    // 16*32*256

// =====================================================================================
// Generic per-patch MPS workgroup.
//   phiP  : [L][F][32]   (this patch, b contiguous)
//   corP  : [L][F][256]  (this patch)
//   labP  : [16][O][16]  (this patch)
//   out   : [32][P][O]
// Thread tile: BT b's x 8 e's of the [32 x 256] mats GEMM; both operands in VGPRs.
// NT = (32/BT)*32 threads.
// =====================================================================================
template<int BT>
DEV void mps_wg(const float* __restrict__ phiP, const float* __restrict__ corP,
                const float* __restrict__ labP, float* __restrict__ out,
                int P, int L, int F, int O, int p)
{
    constexpr int NT = (32 / BT) * 32;
    __shared__ float Msh[32 * 264];   // stride 264: 16B-aligned rows, conflict-light
    __shared__ float vsh[32 * 17];
    __shared__ float lsh[16 * 17];
    const int t  = threadIdx.x;
    const int eg = t & 31;   // 8 consecutive e's
    const int bg = t >> 5;   // BT consecutive b's

    for (int k = t; k < 512; k += NT) vsh[(k >> 4) * 17 + (k & 15)] = 0.25f;  // LB = D^-0.5

    for (int l = 0; l < L; ++l) {
        const float* __restrict__ cPL = corP + (size_t)l * F * 256 + eg * 8;
        const float* __restrict__ pPL = phiP + (size_t)l * F * 32 + bg * BT;
        float acc[BT][8];
        #pragma unroll
        for (int a = 0; a < BT; ++a)
            #pragma unroll
            for (int e = 0; e < 8; ++e) acc[a][e] = 0.f;
        #pragma unroll 2
        for (int f = 0; f < F; ++f) {
            float ce[8], pb[BT];
            #pragma unroll
            for (int e = 0; e < 8; ++e) ce[e] = cPL[f * 256 + e];
            #pragma unroll
            for (int a = 0; a < BT; ++a) pb[a] = pPL[f * 32 + a];
            #pragma unroll
            for (int a = 0; a < BT; ++a)
                #pragma unroll
                for (int e = 0; e < 8; ++e) acc[a][e] = fmaf(pb[a], ce[e], acc[a][e]);
        }
        __syncthreads();                       // prev matvec reads of Msh done
        #pragma unroll
        for (int a = 0; a < BT; ++a)
            #pragma unroll
            for (int e = 0; e < 8; ++e)
                Msh[(bg * BT + a) * 264 + eg * 8 + e] = acc[a][e];
        __syncthreads();
        float wv[512 / NT];
        #pragma unroll
        for (int q = 0; q < 512 / NT; ++q) {
            int k = t + q * NT;
            int b = k >> 4, j = k & 15;
            float s = 0.f;
            #pragma unroll
            for (int i = 0; i < 16; ++i)
                s = fmaf(vsh[b * 17 + i], Msh[b * 264 + i * 16 + j], s);
            wv[q] = s;
        }
        __syncthreads();
        #pragma unroll
        for (int q = 0; q < 512 / NT; ++q) {
            int k = t + q * NT;
            vsh[(k >> 4) * 17 + (k & 15)] = wv[q];
        }
    }
    // epilogue: labelRB[i][o] = 0.25 * sum_j label[i][o][j]
    for (int k = t; k < 256; k += NT) {
        int i = k >> 4, o = k & 15;
        float lr = 0.f;
        if (o < O) {
            const float* lp = labP + ((size_t)i * O + o) * 16;
            #pragma unroll
            for (int j = 0; j < 16; ++j) lr += lp[j];
        }
        lsh[i * 17 + o] = lr * 0.25f;
    }
    __syncthreads();
    for (int k = t; k < 512; k += NT) {
        int b = k >> 4, o = k & 15;
        if (o < O) {
            float s = 0.f;
            #pragma unroll
            for (int i = 0; i < 16; ++i) s = fmaf(vsh[b * 17 + i], lsh[i * 17 + o], s);
            out[((size_t)b * P + p) * O + o] = s;
        }
    }
}

// =====================================================================================
// Stage-1 phi gathers: phi1L [256][4][96][32], phi1C [1024][3][32][32]
// =====================================================================================
__global__ __launch_bounds__(256) void k_phi1(const float* __restrict__ x,
                                              float* __restrict__ phiL,
                                              float* __restrict__ phiC)
{
    int idx = blockIdx.x * 256 + threadIdx.x;
    if (idx < 3145728) {
        int b = idx & 31;
        int r = idx >> 5;
        int f = r % 96; r /= 96;
        int l = r & 3;  int p = r >> 2;
        int C = (f < 48) ? f : f - 48;
        int flat = C * 1024 + p * 4 + l;        // over [3,8,8,16,16]
        int c = flat >> 14, h = (flat >> 11) & 7, w = (flat >> 8) & 7;
        int i = (flat >> 4) & 15, j = flat & 15;
        float v = x[b * 49152 + c * 16384 + (h * 16 + i) * 128 + (w * 16 + j)];
        phiL[idx] = (f < 48) ? v : 1.0f - v;
    } else {
        idx -= 3145728;
        int b = idx & 31;
        int r = idx >> 5;
        int f = r & 31; r >>= 5;
        int l = r % 3;  int p = r / 3;
        int C = (f < 16) ? f : f - 16;
        int flat = C * 3072 + p * 3 + l;        // over [3,32,32,4,4]
        int c = flat >> 14, hb = (flat >> 9) & 31, wb = (flat >> 4) & 31;
        int i = (flat >> 2) & 3, j = flat & 3;
        float v = x[b * 49152 + c * 16384 + (hb * 4 + i) * 128 + (wb * 4 + j)];
        phiC[idx] = (f < 16) ? v : 1.0f - v;
    }
}

// =====================================================================================
// Stage-1 MPS: 256 LoTe patches (L=4,F=96) + 1024 conv patches (L=3,F=32)
// =====================================================================================
__global__ __launch_bounds__(256) void k_mps1(const float* __restrict__ phi1L, const float* __restrict__ phi1C,
    const float* __restrict__ l1c, const float* __restrict__ l1l,
    const float* __restrict__ c1c, const float* __restrict__ c1l,
    float* __restrict__ ly, float* __restrict__ cy)
{
    int wg = blockIdx.x;
    if (wg < 256) {
        int p = wg;
        mps_wg<4>(phi1L + (size_t)p * 12288, l1c + (size_t)p * 98304, l1l + (size_t)p * 4096,
                  ly, 256, 4, 96, 16, p);
    } else {
        int p = wg - 256;
        mps_wg<4>(phi1C + (size_t)p * 3072, c1c + (size_t)p * 24576, c1l + (size_t)p * 4096,
                  cy, 1024, 3, 32, 16, p);
    }
}

// =====================================================================================
// BN stats (training-mode batch stats) -> per-channel scale/shift
// =====================================================================================
__global__ __launch_bounds__(64) void k_bn1(const float* __restrict__ ly, const float* __restrict__ cy,
    const float* __restrict__ g1, const float* __restrict__ b1,
    const float* __restrict__ gc1, const float* __restrict__ bc1,
    float* __restrict__ scL, float* __restrict__ shL,
    float* __restrict__ scC, float* __restrict__ shC)
{
    int ch = blockIdx.x, t = threadIdx.x;
    const float *src, *g, *bb; float *sc, *sh; int cc, stride;
    if (ch < 256) { src = ly; g = g1;  bb = b1;  sc = scL; sh = shL; cc = ch;       stride = 4096;  }
    else          { src = cy; g = gc1; bb = bc1; sc = scC; sh = shC; cc = ch - 256; stride = 16384; }
    int o = t & 15, b0 = t >> 4;
    float s = 0.f, sq = 0.f;
    for (int b = b0; b < 32; b += 4) { float v = src[b * stride + cc * 16 + o]; s += v; sq += v * v; }
    for (int off = 32; off > 0; off >>= 1) { s += __shfl_down(s, off); sq += __shfl_down(sq, off); }
    if (t == 0) {
        float mean = s * (1.f / 512.f);
        float var  = sq * (1.f / 512.f) - mean * mean;
        float scale = rsqrtf(var + 1e-5f) * g[cc];
        sc[cc] = scale; sh[cc] = bb[cc] - mean * scale;
    }
}

// comb[b, ch, p, a]: stage-2 fused input (BN applied on the fly)
DEV float comb_val(const float* __restrict__ ly, const float* __restrict__ cy,
                   const float* __restrict__ scL, const float* __restrict__ shL,
                   const float* __restrict__ scC, const float* __restrict__ shC,
                   int b, int ch, int p, int a)
{
    if (a < 4) {                                  // ly2 branch
        int flat = p * 4 + a;                     // over [2,2,8,8]
        int hb = flat >> 7, wb = (flat >> 6) & 1, i = (flat >> 3) & 7, j = flat & 7;
        int P1 = ch * 16 + hb * 8 + i;
        int s  = wb * 8 + j;
        return ly[b * 4096 + P1 * 16 + s] * scL[P1] + shL[P1];
    } else {                                      // cy2 transposed branch
        int d = a - 4;
        int hb = p >> 3, wb = p & 7;
        int i = ch >> 2, j = ch & 3;
        int r = hb * 4 + i, c = wb * 4 + j;
        int P1 = d * 64 + r * 2 + (c >> 4);
        int o  = c & 15;
        return cy[b * 16384 + P1 * 16 + o] * scC[P1] + shC[P1];
    }
}

__global__ __launch_bounds__(256) void k_phi2(const float* __restrict__ ly, const float* __restrict__ cy,
    const float* __restrict__ scL, const float* __restrict__ shL,
    const float* __restrict__ scC, const float* __restrict__ shC,
    float* __restrict__ phi2L, float* __restrict__ phi2C)
{
    int idx = blockIdx.x * 256 + threadIdx.x;
    if (idx < 1310720) {                 // phi2L [64][20][32][32]
        int b = idx & 31;
        int r = idx >> 5;
        int f = r & 31; r >>= 5;
        int l = r % 20; int p = r / 20;
        int ch = (f < 16) ? f : f - 16;
        float v = comb_val(ly, cy, scL, shL, scC, shC, b, ch, p, l);
        phi2L[idx] = (f < 16) ? v : 1.0f - v;
    } else {                             // phi2C [64][16][40][32]
        int k = idx - 1310720;
        int b = k & 31;
        int r = k >> 5;
        int f = r % 40; r /= 40;
        int l = r & 15; int p = r >> 4;
        int a = (f < 20) ? f : f - 20;
        float v = comb_val(ly, cy, scL, shL, scC, shC, b, l, p, a);
        phi2C[k] = (f < 20) ? v : 1.0f - v;
    }
}

__global__ __launch_bounds__(512) void k_mps2(const float* __restrict__ phi2L, const float* __restrict__ phi2C,
    const float* __restrict__ l2c, const float* __restrict__ l2l,
    const float* __restrict__ c2c, const float* __restrict__ c2l,
    float* __restrict__ lo2, float* __restrict__ co2)
{
    int wg = blockIdx.x;
    if (wg < 64) {
        int p = wg;
        mps_wg<2>(phi2L + (size_t)p * 20480, l2c + (size_t)p * 163840, l2l + (size_t)p * 4096,
                  lo2, 64, 20, 32, 16, p);
    } else {
        int p = wg - 64;
        mps_wg<2>(phi2C + (size_t)p * 20480, c2c + (size_t)p * 163840, c2l + (size_t)p * 4096,
                  co2, 64, 16, 40, 16, p);
    }
}

__global__ __launch_bounds__(64) void k_bn2(const float* __restrict__ lo2, const float* __restrict__ co2,
    const float* __restrict__ g2, const float* __restrict__ b2,
    float* __restrict__ sc2, float* __restrict__ sh2)
{
    int ch = blockIdx.x, t = threadIdx.x;
    int o = t & 31, b0 = t >> 5;
    float s = 0.f, sq = 0.f;
    for (int b = b0; b < 32; b += 2) {
        float v = (o < 16) ? lo2[b * 1024 + ch * 16 + o] : co2[b * 1024 + ch * 16 + (o - 16)];
        s += v; sq += v * v;
    }
    for (int off = 32; off > 0; off >>= 1) { s += __shfl_down(s, off); sq += __shfl_down(sq, off); }
    if (t == 0) {
        float mean = s * (1.f / 1024.f);
        float var  = sq * (1.f / 1024.f) - mean * mean;
        float scale = rsqrtf(var + 1e-5f) * g2[ch];
        sc2[ch] = scale; sh2[ch] = b2[ch] - mean * scale;
    }
}

// grid[b, ch(32), r, c] with BN2 applied on the fly
DEV float grid_val(const float* __restrict__ lo2, const float* __restrict__ co2,
                   const float* __restrict__ sc2, const float* __restrict__ sh2,
                   int b, int ch, int r, int c)
{
    int rc = r * 8 + c;
    int p = ch * 2 + (rc >> 5);
    int o = rc & 31;
    float v = (o < 16) ? lo2[b * 1024 + p * 16 + o] : co2[b * 1024 + p * 16 + (o - 16)];
    return v * sc2[p] + sh2[p];
}

__global__ __launch_bounds__(256) void k_phi3(const float* __restrict__ lo2, const float* __restrict__ co2,
    const float* __restrict__ sc2, const float* __restrict__ sh2,
    float* __restrict__ phi3L, float* __restrict__ phi3C)
{
    int idx = blockIdx.x * 256 + threadIdx.x;
    if (idx < 131072) {                  // phi3L [16][4][64][32]
        int b = idx & 31;
        int r = idx >> 5;
        int f = r & 63; r >>= 6;
        int l = r & 3;  int p = r >> 2;
        int ch = (f < 32) ? f : f - 32;
        int flat = p * 4 + l;            // over [2,2,4,4]
        int hb = flat >> 5, wb = (flat >> 4) & 1, i = (flat >> 2) & 3, j = flat & 3;
        float v = grid_val(lo2, co2, sc2, sh2, b, ch, hb * 4 + i, wb * 4 + j);
        phi3L[idx] = (f < 32) ? v : 1.0f - v;
    } else {                             // phi3C [16][32][8][32]
        int k = idx - 131072;
        int b = k & 31;
        int r = k >> 5;
        int f = r & 7;  r >>= 3;
        int l = r & 31; int p = r >> 5;
        int f4 = (f < 4) ? f : f - 4;
        int c32 = f4 * 8 + (p >> 1);
        int hb = (p & 1) * 2 + (l >> 4);
        int wb = (l >> 2) & 3;
        int i = (l >> 1) & 1, j = l & 1;
        float v = grid_val(lo2, co2, sc2, sh2, b, c32, hb * 2 + i, wb * 2 + j);
        phi3C[k] = (f < 4) ? v : 1.0f - v;
    }
}

__global__ __launch_bounds__(512) void k_mps3(const float* __restrict__ phi3L, const float* __restrict__ phi3C,
    const float* __restrict__ l3c, const float* __restrict__ l3l,
    const float* __restrict__ c3c, const float* __restrict__ c3l,
    float* __restrict__ lo3, float* __restrict__ co3)
{
    int wg = blockIdx.x;
    if (wg < 16) {
        int p = wg;
        mps_wg<2>(phi3L + (size_t)p * 8192, l3c + (size_t)p * 65536, l3l + (size_t)p * 4096,
                  lo3, 16, 4, 64, 16, p);
    } else {
        int p = wg - 16;
        mps_wg<2>(phi3C + (size_t)p * 8192, c3c + (size_t)p * 65536, c3l + (size_t)p * 4096,
                  co3, 16, 32, 8, 16, p);
    }
}

// BN3 stats + final-phi build, single workgroup
__global__ __launch_bounds__(256) void k_bn3_phiF(const float* __restrict__ lo3, const float* __restrict__ co3,
    const float* __restrict__ g3, const float* __restrict__ b3,
    float* __restrict__ phiF)
{
    __shared__ float sc3[16], sh3[16];
    int t = threadIdx.x;
    int ch = t >> 4, r = t & 15;
    float s = 0.f, sq = 0.f;
    for (int k2 = 0; k2 < 64; ++k2) {
        int v = r * 64 + k2;
        int b = v >> 5, o = v & 31;
        float x = (o < 16) ? lo3[b * 256 + ch * 16 + o] : co3[b * 256 + ch * 16 + (o - 16)];
        s += x; sq += x * x;
    }
    for (int off = 8; off > 0; off >>= 1) { s += __shfl_down(s, off, 16); sq += __shfl_down(sq, off, 16); }
    if (r == 0) {
        float mean = s * (1.f / 1024.f);
        float var  = sq * (1.f / 1024.f) - mean * mean;
        float scale = rsqrtf(var + 1e-5f) * g3[ch];
        sc3[ch] = scale; sh3[ch] = b3[ch] - mean * scale;
    }
    __syncthreads();
    // phiF [16][64][32]: phiF(l,f,b): f<32 -> bn3[b, p=l, o=f], else 1 - bn3[b, l, f-32]
    for (int k = t; k < 32768; k += 256) {
        int b = k & 31;
        int rr = k >> 5;
        int f = rr & 63;
        int l = rr >> 6;
        int o = (f < 32) ? f : f - 32;
        float raw = (o < 16) ? lo3[b * 256 + l * 16 + o] : co3[b * 256 + l * 16 + (o - 16)];
        float v = raw * sc3[l] + sh3[l];
        phiF[k] = (f < 32) ? v : 1.0f - v;
    }
}

// Final MPS phase A: build M_l (parallel over l); phase B: serial chain, 1 WG
__global__ __launch_bounds__(256) void k_mpsF_build(const float* __restrict__ phiF,
    const float* __restrict__ fc, float* __restrict__ MF)
{
    int l = blockIdx.x;
    int t = threadIdx.x, eg = t & 31, bg = t >> 5;
    const float* __restrict__ cPL = fc + (size_t)l * 16384 + eg * 8;
    const float* __restrict__ pPL = phiF + (size_t)l * 2048 + bg * 4;
    float acc[4][8];
    #pragma unroll
    for (int a = 0; a < 4; ++a)
        #pragma unroll
        for (int e = 0; e < 8; ++e) acc[a][e] = 0.f;
    #pragma unroll 2
    for (int f = 0; f < 64; ++f) {
        float ce[8], pb[4];
        #pragma unroll
        for (int e = 0; e < 8; ++e) ce[e] = cPL[f * 256 + e];
        #pragma unroll
        for (int a = 0; a < 4; ++a) pb[a] = pPL[f * 32 + a];
        #pragma unroll
        for (int a = 0; a < 4; ++a)
            #pragma unroll
            for (int e = 0; e < 8; ++e) acc[a][e] = fmaf(pb[a], ce[e], acc[a][e]);
    }
    #pragma unroll
    for (int a = 0; a < 4; ++a)
        #pragma unroll
        for (int e = 0; e < 8; ++e)
            MF[(size_t)(l * 32 + bg * 4 + a) * 256 + eg * 8 + e] = acc[a][e];
}

__global__ __launch_bounds__(256) void k_mpsF_chain(const float* __restrict__ MF,
    const float* __restrict__ fl, float* __restrict__ out)
{
    __shared__ float Msh[32 * 264];
    __shared__ float vsh[32 * 17];
    __shared__ float lsh[16 * 17];
    int t = threadIdx.x;
    for (int k = t; k < 512; k += 256) vsh[(k >> 4) * 17 + (k & 15)] = 0.25f;
    for (int l = 0; l < 16; ++l) {
        __syncthreads();
        for (int k = t; k < 8192; k += 256) {
            int b = k >> 8, e = k & 255;
            Msh[b * 264 + e] = MF[l * 8192 + k];
        }
        __syncthreads();
        float wv[2];
        #pragma unroll
        for (int q = 0; q < 2; ++q) {
            int k = t + q * 256;
            int b = k >> 4, j = k & 15;
            float s = 0.f;
            #pragma unroll
            for (int i = 0; i < 16; ++i) s = fmaf(vsh[b * 17 + i], Msh[b * 264 + i * 16 + j], s);
            wv[q] = s;
        }
        __syncthreads();
        #pragma unroll
        for (int q = 0; q < 2; ++q) { int k = t + q * 256; vsh[(k >> 4) * 17 + (k & 15)] = wv[q]; }
    }
    {
        int i = t >> 4, o = t & 15;
        float lr = 0.f;
        if (o < 10) {
            const float* lp = fl + ((size_t)i * 10 + o) * 16;
            #pragma unroll
            for (int j = 0; j < 16; ++j) lr += lp[j];
        }
        lsh[i * 17 + o] = lr * 0.25f;
    }
    __syncthreads();
    for (int k = t; k < 512; k += 256) {
        int b = k >> 4, o = k & 15;
        if (o < 10) {
            float s = 0.f;
            #pragma unroll
            for (int i = 0; i < 16; ++i) s = fmaf(vsh[b * 17 + i], lsh[i * 17 + o], s);
            out[b * 10 + o] = s;
        }
    }
}

extern "C" void kernel_launch(void* const* d_in, const int* in_sizes, int n_in,
                              void* d_out, int out_size, void* d_ws, size_t ws_size,
                              hipStream_t stream) {
    const float* x   = (const float*)d_in[0];
    const float* l1c = (const float*)d_in[1];
    const float* l1l = (const float*)d_in[2];
    const float* c1c = (const float*)d_in[3];
    const float* c1l = (const float*)d_in[4];
    const float* l2c = (const float*)d_in[5];
    const float* l2l = (const float*)d_in[6];
    const float* c2c = (const float*)d_in[7];
    const float* c2l = (const float*)d_in[8];
    const float* l3c = (const float*)d_in[9];
    const float* l3l = (const float*)d_in[10];
    const float* c3c = (const float*)d_in[11];
    const float* c3l = (const float*)d_in[12];
    const float* fc  = (const float*)d_in[13];
    const float* fl  = (const float*)d_in[14];
    const float* g1  = (const float*)d_in[15];
    const float* b1  = (const float*)d_in[16];
    const float* gc1 = (const float*)d_in[17];
    const float* bc1 = (const float*)d_in[18];
    const float* g2  = (const float*)d_in[19];
    const float* b2  = (const float*)d_in[20];
    const float* g3  = (const float*)d_in[21];
    const float* b3  = (const float*)d_in[22];
    float* ws  = (float*)d_ws;   // needs 40,315,392 bytes
    float* out = (float*)d_out;

    k_phi1<<<24576, 256, 0, stream>>>(x, ws + W_PHI1L, ws + W_PHI1C);
    k_mps1<<<1280, 256, 0, stream>>>(ws + W_PHI1L, ws + W_PHI1C, l1c, l1l, c1c, c1l,
                                     ws + W_LY, ws + W_CY);
    k_bn1<<<1280, 64, 0, stream>>>(ws + W_LY, ws + W_CY, g1, b1, gc1, bc1,
                                   ws + W_SCL, ws + W_SHL, ws + W_SCC, ws + W_SHC);
    k_phi2<<<10240, 256, 0, stream>>>(ws + W_LY, ws + W_CY, ws + W_SCL, ws + W_SHL,
                                      ws + W_SCC, ws + W_SHC, ws + W_PHI2L, ws + W_PHI2C);
    k_mps2<<<128, 512, 0, stream>>>(ws + W_PHI2L, ws + W_PHI2C, l2c, l2l, c2c, c2l,
                                    ws + W_LO2, ws + W_CO2);
    k_bn2<<<64, 64, 0, stream>>>(ws + W_LO2, ws + W_CO2, g2, b2, ws + W_SC2, ws + W_SH2);
    k_phi3<<<1024, 256, 0, stream>>>(ws + W_LO2, ws + W_CO2, ws + W_SC2, ws + W_SH2,
                                     ws + W_PHI3L, ws + W_PHI3C);
    k_mps3<<<32, 512, 0, stream>>>(ws + W_PHI3L, ws + W_PHI3C, l3c, l3l, c3c, c3l,
                                   ws + W_LO3, ws + W_CO3);
    k_bn3_phiF<<<1, 256, 0, stream>>>(ws + W_LO3, ws + W_CO3, g3, b3, ws + W_PHIF);
    k_mpsF_build<<<16, 256, 0, stream>>>(ws + W_PHIF, fc, ws + W_MF);
    k_mpsF_chain<<<1, 256, 0, stream>>>(ws + W_MF, fl, out);
}

// Round 2
// 633.575 us; speedup vs baseline: 1.2416x; 1.2416x over previous
//
#include <hip/hip_runtime.h>

#define DEV __device__ __forceinline__

// ---------------- workspace layout (float offsets) ----------------
// [0, 3,145,728)          phi1L            (dead after k_mps1)  -> reused: phi2L/phi2C
// [3,145,728, 6,291,456)  phi1C            (dead after k_mps1)  -> reused: labRB + stage2/3 smalls
// [6,291,456, 6,949,376)  ly/cy/bn1 scales (dead after k_phi2)
// [6,949,376, ...)        MATS buffer (chunk-sized by ws_size, reused for all build/chain pairs)
#define W_PHI1L 0u
#define W_PHI1C 3145728u
#define W_LY    6291456u
#define W_CY    6422528u
#define W_SCL   6946816u
#define W_SHL   6947072u
#define W_SCC   6947328u
#define W_SHC   6948352u
#define W_MATS  6949376u

#define W_PHI2L 0u
#define W_PHI2C 1310720u

#define W_LR2L  3145728u   // 64*256
#define W_LR2C  3162112u   // 64*256
#define W_LR3L  3178496u   // 16*256
#define W_LR3C  3182592u   // 16*256
#define W_LO2   3186688u   // 32768
#define W_CO2   3219456u   // 32768
#define W_SC2   3252224u   // 64
#define W_SH2   3252288u   // 64
#define W_PHI3L 3252352u   // 131072
#define W_PHI3C 3383424u   // 131072
#define W_LO3   3514496u   // 8192
#define W_CO3   3522688u   // 8192
#define W_PHIF  3530880u   // 32768
#define W_MF    3563648u   // 131072

// =====================================================================================
// Fused per-patch MPS workgroup (stage 1 only: enough WGs there to stay occupied).
// =====================================================================================
template<int BT>
DEV void mps_wg(const float* __restrict__ phiP, const float* __restrict__ corP,
                const float* __restrict__ labP, float* __restrict__ out,
                int P, int L, int F, int O, int p)
{
    constexpr int NT = (32 / BT) * 32;
    __shared__ float Msh[32 * 264];
    __shared__ float vsh[32 * 17];
    __shared__ float lsh[16 * 17];
    const int t  = threadIdx.x;
    const int eg = t & 31;
    const int bg = t >> 5;

    for (int k = t; k < 512; k += NT) vsh[(k >> 4) * 17 + (k & 15)] = 0.25f;

    for (int l = 0; l < L; ++l) {
        const float* __restrict__ cPL = corP + (size_t)l * F * 256 + eg * 8;
        const float* __restrict__ pPL = phiP + (size_t)l * F * 32 + bg * BT;
        float acc[BT][8];
        #pragma unroll
        for (int a = 0; a < BT; ++a)
            #pragma unroll
            for (int e = 0; e < 8; ++e) acc[a][e] = 0.f;
        #pragma unroll 2
        for (int f = 0; f < F; ++f) {
            float ce[8], pb[BT];
            #pragma unroll
            for (int e = 0; e < 8; ++e) ce[e] = cPL[f * 256 + e];
            #pragma unroll
            for (int a = 0; a < BT; ++a) pb[a] = pPL[f * 32 + a];
            #pragma unroll
            for (int a = 0; a < BT; ++a)
                #pragma unroll
                for (int e = 0; e < 8; ++e) acc[a][e] = fmaf(pb[a], ce[e], acc[a][e]);
        }
        __syncthreads();
        #pragma unroll
        for (int a = 0; a < BT; ++a)
            #pragma unroll
            for (int e = 0; e < 8; ++e)
                Msh[(bg * BT + a) * 264 + eg * 8 + e] = acc[a][e];
        __syncthreads();
        float wv[512 / NT];
        #pragma unroll
        for (int q = 0; q < 512 / NT; ++q) {
            int k = t + q * NT;
            int b = k >> 4, j = k & 15;
            float s = 0.f;
            #pragma unroll
            for (int i = 0; i < 16; ++i)
                s = fmaf(vsh[b * 17 + i], Msh[b * 264 + i * 16 + j], s);
            wv[q] = s;
        }
        __syncthreads();
        #pragma unroll
        for (int q = 0; q < 512 / NT; ++q) {
            int k = t + q * NT;
            vsh[(k >> 4) * 17 + (k & 15)] = wv[q];
        }
    }
    for (int k = t; k < 256; k += NT) {
        int i = k >> 4, o = k & 15;
        float lr = 0.f;
        if (o < O) {
            const float* lp = labP + ((size_t)i * O + o) * 16;
            #pragma unroll
            for (int j = 0; j < 16; ++j) lr += lp[j];
        }
        lsh[i * 17 + o] = lr * 0.25f;
    }
    __syncthreads();
    for (int k = t; k < 512; k += NT) {
        int b = k >> 4, o = k & 15;
        if (o < O) {
            float s = 0.f;
            #pragma unroll
            for (int i = 0; i < 16; ++i) s = fmaf(vsh[b * 17 + i], lsh[i * 17 + o], s);
            out[((size_t)b * P + p) * O + o] = s;
        }
    }
}

// =====================================================================================
// Generic mats build: one WG per (p,l). mats[(p-p0)*L + l][b][i*16+j]
// =====================================================================================
template<int L, int F>
__global__ __launch_bounds__(256) void k_build(const float* __restrict__ phi,
    const float* __restrict__ cores, float* __restrict__ mats, int p0)
{
    const int wg = blockIdx.x;
    const int pl = wg / L;
    const int l  = wg % L;
    const int p  = p0 + pl;
    const int t  = threadIdx.x;
    const int eg = t & 31;
    const int bg = t >> 5;
    const float* __restrict__ cPL = cores + (((size_t)p * L + l) * F) * 256 + eg * 8;
    const float* __restrict__ pPL = phi   + (((size_t)p * L + l) * F) * 32  + bg * 4;
    float acc[4][8];
    #pragma unroll
    for (int a = 0; a < 4; ++a)
        #pragma unroll
        for (int e = 0; e < 8; ++e) acc[a][e] = 0.f;
    #pragma unroll 2
    for (int f = 0; f < F; ++f) {
        float4 c0 = *reinterpret_cast<const float4*>(cPL + f * 256);
        float4 c1 = *reinterpret_cast<const float4*>(cPL + f * 256 + 4);
        float4 pb = *reinterpret_cast<const float4*>(pPL + f * 32);
        float ce[8] = {c0.x, c0.y, c0.z, c0.w, c1.x, c1.y, c1.z, c1.w};
        float pv[4] = {pb.x, pb.y, pb.z, pb.w};
        #pragma unroll
        for (int a = 0; a < 4; ++a)
            #pragma unroll
            for (int e = 0; e < 8; ++e) acc[a][e] = fmaf(pv[a], ce[e], acc[a][e]);
    }
    float* __restrict__ mout = mats + ((size_t)pl * L + l) * 8192 + eg * 8;
    #pragma unroll
    for (int a = 0; a < 4; ++a) {
        float4 s0 = {acc[a][0], acc[a][1], acc[a][2], acc[a][3]};
        float4 s1 = {acc[a][4], acc[a][5], acc[a][6], acc[a][7]};
        *reinterpret_cast<float4*>(mout + (bg * 4 + a) * 256)     = s0;
        *reinterpret_cast<float4*>(mout + (bg * 4 + a) * 256 + 4) = s1;
    }
}

// =====================================================================================
// Generic chain: one 16-lane group per (p,b). Register prefetch of M_{l+1}.
// out[b][Ptot][16]; labRB[p][i][o] precontracted (x0.25 RB).
// =====================================================================================
template<int L>
__global__ __launch_bounds__(256) void k_chain(const float* __restrict__ mats,
    const float* __restrict__ labRB, float* __restrict__ out, int p0, int Ptot)
{
    const int t   = threadIdx.x;
    const int grp = (blockIdx.x * 256 + t) >> 4;
    const int j   = t & 15;
    const int pl  = grp >> 5;
    const int b   = grp & 31;
    const float* __restrict__ mb = mats + (size_t)pl * L * 8192 + b * 256 + j;
    float v = 0.25f;
    float m[16];
    #pragma unroll
    for (int i = 0; i < 16; ++i) m[i] = mb[i * 16];
    #pragma unroll
    for (int l = 0; l < L; ++l) {
        float nm[16];
        if (l + 1 < L) {
            const float* __restrict__ nb = mb + (size_t)(l + 1) * 8192;
            #pragma unroll
            for (int i = 0; i < 16; ++i) nm[i] = nb[i * 16];
        }
        float w = 0.f;
        #pragma unroll
        for (int i = 0; i < 16; ++i) w = fmaf(__shfl(v, i, 16), m[i], w);
        v = w;
        #pragma unroll
        for (int i = 0; i < 16; ++i) m[i] = nm[i];
    }
    const float* __restrict__ lr = labRB + (size_t)(p0 + pl) * 256 + j;
    float s = 0.f;
    #pragma unroll
    for (int i = 0; i < 16; ++i) s = fmaf(__shfl(v, i, 16), lr[i * 16], s);
    out[((size_t)b * Ptot + (p0 + pl)) * 16 + j] = s;
}

// Precontract labels with RB: labRB[p][i][o] = 0.25 * sum_j lab[p][i][o][j]
__global__ __launch_bounds__(256) void k_labRB(const float* __restrict__ l2l,
    const float* __restrict__ c2l, const float* __restrict__ l3l,
    const float* __restrict__ c3l, float* __restrict__ ws)
{
    int idx = blockIdx.x * 256 + threadIdx.x;   // < 40960
    const float* src; float* dst; int e;
    if (idx < 16384)       { src = l2l; dst = ws + W_LR2L; e = idx; }
    else if (idx < 32768)  { src = c2l; dst = ws + W_LR2C; e = idx - 16384; }
    else if (idx < 36864)  { src = l3l; dst = ws + W_LR3L; e = idx - 32768; }
    else                   { src = c3l; dst = ws + W_LR3C; e = idx - 36864; }
    const float* lp = src + (size_t)e * 16;
    float s = 0.f;
    #pragma unroll
    for (int jj = 0; jj < 16; ++jj) s += lp[jj];
    dst[e] = s * 0.25f;
}

// =====================================================================================
// Stage-1 phi gathers
// =====================================================================================
__global__ __launch_bounds__(256) void k_phi1(const float* __restrict__ x,
                                              float* __restrict__ phiL,
                                              float* __restrict__ phiC)
{
    int idx = blockIdx.x * 256 + threadIdx.x;
    if (idx < 3145728) {
        int b = idx & 31;
        int r = idx >> 5;
        int f = r % 96; r /= 96;
        int l = r & 3;  int p = r >> 2;
        int C = (f < 48) ? f : f - 48;
        int flat = C * 1024 + p * 4 + l;
        int c = flat >> 14, h = (flat >> 11) & 7, w = (flat >> 8) & 7;
        int i = (flat >> 4) & 15, j = flat & 15;
        float v = x[b * 49152 + c * 16384 + (h * 16 + i) * 128 + (w * 16 + j)];
        phiL[idx] = (f < 48) ? v : 1.0f - v;
    } else {
        idx -= 3145728;
        int b = idx & 31;
        int r = idx >> 5;
        int f = r & 31; r >>= 5;
        int l = r % 3;  int p = r / 3;
        int C = (f < 16) ? f : f - 16;
        int flat = C * 3072 + p * 3 + l;
        int c = flat >> 14, hb = (flat >> 9) & 31, wb = (flat >> 4) & 31;
        int i = (flat >> 2) & 3, j = flat & 3;
        float v = x[b * 49152 + c * 16384 + (hb * 4 + i) * 128 + (wb * 4 + j)];
        phiC[idx] = (f < 16) ? v : 1.0f - v;
    }
}

__global__ __launch_bounds__(256) void k_mps1(const float* __restrict__ phi1L, const float* __restrict__ phi1C,
    const float* __restrict__ l1c, const float* __restrict__ l1l,
    const float* __restrict__ c1c, const float* __restrict__ c1l,
    float* __restrict__ ly, float* __restrict__ cy)
{
    int wg = blockIdx.x;
    if (wg < 256) {
        int p = wg;
        mps_wg<4>(phi1L + (size_t)p * 12288, l1c + (size_t)p * 98304, l1l + (size_t)p * 4096,
                  ly, 256, 4, 96, 16, p);
    } else {
        int p = wg - 256;
        mps_wg<4>(phi1C + (size_t)p * 3072, c1c + (size_t)p * 24576, c1l + (size_t)p * 4096,
                  cy, 1024, 3, 32, 16, p);
    }
}

__global__ __launch_bounds__(64) void k_bn1(const float* __restrict__ ly, const float* __restrict__ cy,
    const float* __restrict__ g1, const float* __restrict__ b1,
    const float* __restrict__ gc1, const float* __restrict__ bc1,
    float* __restrict__ scL, float* __restrict__ shL,
    float* __restrict__ scC, float* __restrict__ shC)
{
    int ch = blockIdx.x, t = threadIdx.x;
    const float *src, *g, *bb; float *sc, *sh; int cc, stride;
    if (ch < 256) { src = ly; g = g1;  bb = b1;  sc = scL; sh = shL; cc = ch;       stride = 4096;  }
    else          { src = cy; g = gc1; bb = bc1; sc = scC; sh = shC; cc = ch - 256; stride = 16384; }
    int o = t & 15, b0 = t >> 4;
    float s = 0.f, sq = 0.f;
    for (int b = b0; b < 32; b += 4) { float v = src[b * stride + cc * 16 + o]; s += v; sq += v * v; }
    for (int off = 32; off > 0; off >>= 1) { s += __shfl_down(s, off); sq += __shfl_down(sq, off); }
    if (t == 0) {
        float mean = s * (1.f / 512.f);
        float var  = sq * (1.f / 512.f) - mean * mean;
        float scale = rsqrtf(var + 1e-5f) * g[cc];
        sc[cc] = scale; sh[cc] = bb[cc] - mean * scale;
    }
}

DEV float comb_val(const float* __restrict__ ly, const float* __restrict__ cy,
                   const float* __restrict__ scL, const float* __restrict__ shL,
                   const float* __restrict__ scC, const float* __restrict__ shC,
                   int b, int ch, int p, int a)
{
    if (a < 4) {
        int flat = p * 4 + a;
        int hb = flat >> 7, wb = (flat >> 6) & 1, i = (flat >> 3) & 7, j = flat & 7;
        int P1 = ch * 16 + hb * 8 + i;
        int s  = wb * 8 + j;
        return ly[b * 4096 + P1 * 16 + s] * scL[P1] + shL[P1];
    } else {
        int d = a - 4;
        int hb = p >> 3, wb = p & 7;
        int i = ch >> 2, j = ch & 3;
        int r = hb * 4 + i, c = wb * 4 + j;
        int P1 = d * 64 + r * 2 + (c >> 4);
        int o  = c & 15;
        return cy[b * 16384 + P1 * 16 + o] * scC[P1] + shC[P1];
    }
}

__global__ __launch_bounds__(256) void k_phi2(const float* __restrict__ ly, const float* __restrict__ cy,
    const float* __restrict__ scL, const float* __restrict__ shL,
    const float* __restrict__ scC, const float* __restrict__ shC,
    float* __restrict__ phi2L, float* __restrict__ phi2C)
{
    int idx = blockIdx.x * 256 + threadIdx.x;
    if (idx < 1310720) {
        int b = idx & 31;
        int r = idx >> 5;
        int f = r & 31; r >>= 5;
        int l = r % 20; int p = r / 20;
        int ch = (f < 16) ? f : f - 16;
        float v = comb_val(ly, cy, scL, shL, scC, shC, b, ch, p, l);
        phi2L[idx] = (f < 16) ? v : 1.0f - v;
    } else {
        int k = idx - 1310720;
        int b = k & 31;
        int r = k >> 5;
        int f = r % 40; r /= 40;
        int l = r & 15; int p = r >> 4;
        int a = (f < 20) ? f : f - 20;
        float v = comb_val(ly, cy, scL, shL, scC, shC, b, l, p, a);
        phi2C[k] = (f < 20) ? v : 1.0f - v;
    }
}

__global__ __launch_bounds__(64) void k_bn2(const float* __restrict__ lo2, const float* __restrict__ co2,
    const float* __restrict__ g2, const float* __restrict__ b2,
    float* __restrict__ sc2, float* __restrict__ sh2)
{
    int ch = blockIdx.x, t = threadIdx.x;
    int o = t & 31, b0 = t >> 5;
    float s = 0.f, sq = 0.f;
    for (int b = b0; b < 32; b += 2) {
        float v = (o < 16) ? lo2[b * 1024 + ch * 16 + o] : co2[b * 1024 + ch * 16 + (o - 16)];
        s += v; sq += v * v;
    }
    for (int off = 32; off > 0; off >>= 1) { s += __shfl_down(s, off); sq += __shfl_down(sq, off); }
    if (t == 0) {
        float mean = s * (1.f / 1024.f);
        float var  = sq * (1.f / 1024.f) - mean * mean;
        float scale = rsqrtf(var + 1e-5f) * g2[ch];
        sc2[ch] = scale; sh2[ch] = b2[ch] - mean * scale;
    }
}

DEV float grid_val(const float* __restrict__ lo2, const float* __restrict__ co2,
                   const float* __restrict__ sc2, const float* __restrict__ sh2,
                   int b, int ch, int r, int c)
{
    int rc = r * 8 + c;
    int p = ch * 2 + (rc >> 5);
    int o = rc & 31;
    float v = (o < 16) ? lo2[b * 1024 + p * 16 + o] : co2[b * 1024 + p * 16 + (o - 16)];
    return v * sc2[p] + sh2[p];
}

__global__ __launch_bounds__(256) void k_phi3(const float* __restrict__ lo2, const float* __restrict__ co2,
    const float* __restrict__ sc2, const float* __restrict__ sh2,
    float* __restrict__ phi3L, float* __restrict__ phi3C)
{
    int idx = blockIdx.x * 256 + threadIdx.x;
    if (idx < 131072) {
        int b = idx & 31;
        int r = idx >> 5;
        int f = r & 63; r >>= 6;
        int l = r & 3;  int p = r >> 2;
        int ch = (f < 32) ? f : f - 32;
        int flat = p * 4 + l;
        int hb = flat >> 5, wb = (flat >> 4) & 1, i = (flat >> 2) & 3, j = flat & 3;
        float v = grid_val(lo2, co2, sc2, sh2, b, ch, hb * 4 + i, wb * 4 + j);
        phi3L[idx] = (f < 32) ? v : 1.0f - v;
    } else {
        int k = idx - 131072;
        int b = k & 31;
        int r = k >> 5;
        int f = r & 7;  r >>= 3;
        int l = r & 31; int p = r >> 5;
        int f4 = (f < 4) ? f : f - 4;
        int c32 = f4 * 8 + (p >> 1);
        int hb = (p & 1) * 2 + (l >> 4);
        int wb = (l >> 2) & 3;
        int i = (l >> 1) & 1, j = l & 1;
        float v = grid_val(lo2, co2, sc2, sh2, b, c32, hb * 2 + i, wb * 2 + j);
        phi3C[k] = (f < 4) ? v : 1.0f - v;
    }
}

__global__ __launch_bounds__(256) void k_bn3_phiF(const float* __restrict__ lo3, const float* __restrict__ co3,
    const float* __restrict__ g3, const float* __restrict__ b3,
    float* __restrict__ phiF)
{
    __shared__ float sc3[16], sh3[16];
    int t = threadIdx.x;
    int ch = t >> 4, r = t & 15;
    float s = 0.f, sq = 0.f;
    for (int k2 = 0; k2 < 64; ++k2) {
        int v = r * 64 + k2;
        int b = v >> 5, o = v & 31;
        float x = (o < 16) ? lo3[b * 256 + ch * 16 + o] : co3[b * 256 + ch * 16 + (o - 16)];
        s += x; sq += x * x;
    }
    for (int off = 8; off > 0; off >>= 1) { s += __shfl_down(s, off, 16); sq += __shfl_down(sq, off, 16); }
    if (r == 0) {
        float mean = s * (1.f / 1024.f);
        float var  = sq * (1.f / 1024.f) - mean * mean;
        float scale = rsqrtf(var + 1e-5f) * g3[ch];
        sc3[ch] = scale; sh3[ch] = b3[ch] - mean * scale;
    }
    __syncthreads();
    for (int k = t; k < 32768; k += 256) {
        int b = k & 31;
        int rr = k >> 5;
        int f = rr & 63;
        int l = rr >> 6;
        int o = (f < 32) ? f : f - 32;
        float raw = (o < 16) ? lo3[b * 256 + l * 16 + o] : co3[b * 256 + l * 16 + (o - 16)];
        float v = raw * sc3[l] + sh3[l];
        phiF[k] = (f < 32) ? v : 1.0f - v;
    }
}

__global__ __launch_bounds__(256) void k_mpsF_build(const float* __restrict__ phiF,
    const float* __restrict__ fc, float* __restrict__ MF)
{
    int l = blockIdx.x;
    int t = threadIdx.x, eg = t & 31, bg = t >> 5;
    const float* __restrict__ cPL = fc + (size_t)l * 16384 + eg * 8;
    const float* __restrict__ pPL = phiF + (size_t)l * 2048 + bg * 4;
    float acc[4][8];
    #pragma unroll
    for (int a = 0; a < 4; ++a)
        #pragma unroll
        for (int e = 0; e < 8; ++e) acc[a][e] = 0.f;
    #pragma unroll 2
    for (int f = 0; f < 64; ++f) {
        float ce[8], pb[4];
        #pragma unroll
        for (int e = 0; e < 8; ++e) ce[e] = cPL[f * 256 + e];
        #pragma unroll
        for (int a = 0; a < 4; ++a) pb[a] = pPL[f * 32 + a];
        #pragma unroll
        for (int a = 0; a < 4; ++a)
            #pragma unroll
            for (int e = 0; e < 8; ++e) acc[a][e] = fmaf(pb[a], ce[e], acc[a][e]);
    }
    #pragma unroll
    for (int a = 0; a < 4; ++a)
        #pragma unroll
        for (int e = 0; e < 8; ++e)
            MF[(size_t)(l * 32 + bg * 4 + a) * 256 + eg * 8 + e] = acc[a][e];
}

__global__ __launch_bounds__(256) void k_mpsF_chain(const float* __restrict__ MF,
    const float* __restrict__ fl, float* __restrict__ out)
{
    __shared__ float Msh[32 * 264];
    __shared__ float vsh[32 * 17];
    __shared__ float lsh[16 * 17];
    int t = threadIdx.x;
    for (int k = t; k < 512; k += 256) vsh[(k >> 4) * 17 + (k & 15)] = 0.25f;
    for (int l = 0; l < 16; ++l) {
        __syncthreads();
        for (int k = t; k < 8192; k += 256) {
            int b = k >> 8, e = k & 255;
            Msh[b * 264 + e] = MF[l * 8192 + k];
        }
        __syncthreads();
        float wv[2];
        #pragma unroll
        for (int q = 0; q < 2; ++q) {
            int k = t + q * 256;
            int b = k >> 4, j = k & 15;
            float s = 0.f;
            #pragma unroll
            for (int i = 0; i < 16; ++i) s = fmaf(vsh[b * 17 + i], Msh[b * 264 + i * 16 + j], s);
            wv[q] = s;
        }
        __syncthreads();
        #pragma unroll
        for (int q = 0; q < 2; ++q) { int k = t + q * 256; vsh[(k >> 4) * 17 + (k & 15)] = wv[q]; }
    }
    {
        int i = t >> 4, o = t & 15;
        float lr = 0.f;
        if (o < 10) {
            const float* lp = fl + ((size_t)i * 10 + o) * 16;
            #pragma unroll
            for (int j = 0; j < 16; ++j) lr += lp[j];
        }
        lsh[i * 17 + o] = lr * 0.25f;
    }
    __syncthreads();
    for (int k = t; k < 512; k += 256) {
        int b = k >> 4, o = k & 15;
        if (o < 10) {
            float s = 0.f;
            #pragma unroll
            for (int i = 0; i < 16; ++i) s = fmaf(vsh[b * 17 + i], lsh[i * 17 + o], s);
            out[b * 10 + o] = s;
        }
    }
}

// helper: run build+chain pairs for one side, chunked to fit mats buffer
template<int L, int F>
static void run_side(const float* phi, const float* cores, float* mats,
                     const float* labRB, float* out, int P, int Ptot,
                     int maxp, hipStream_t stream)
{
    for (int p0 = 0; p0 < P; p0 += maxp) {
        int np = (P - p0 < maxp) ? (P - p0) : maxp;
        k_build<L, F><<<np * L, 256, 0, stream>>>(phi, cores, mats, p0);
        k_chain<L><<<np * 2, 256, 0, stream>>>(mats, labRB, out, p0, Ptot);
    }
}

extern "C" void kernel_launch(void* const* d_in, const int* in_sizes, int n_in,
                              void* d_out, int out_size, void* d_ws, size_t ws_size,
                              hipStream_t stream) {
    const float* x   = (const float*)d_in[0];
    const float* l1c = (const float*)d_in[1];
    const float* l1l = (const float*)d_in[2];
    const float* c1c = (const float*)d_in[3];
    const float* c1l = (const float*)d_in[4];
    const float* l2c = (const float*)d_in[5];
    const float* l2l = (const float*)d_in[6];
    const float* c2c = (const float*)d_in[7];
    const float* c2l = (const float*)d_in[8];
    const float* l3c = (const float*)d_in[9];
    const float* l3l = (const float*)d_in[10];
    const float* c3c = (const float*)d_in[11];
    const float* c3l = (const float*)d_in[12];
    const float* fc  = (const float*)d_in[13];
    const float* fl  = (const float*)d_in[14];
    const float* g1  = (const float*)d_in[15];
    const float* b1  = (const float*)d_in[16];
    const float* gc1 = (const float*)d_in[17];
    const float* bc1 = (const float*)d_in[18];
    const float* g2  = (const float*)d_in[19];
    const float* b2  = (const float*)d_in[20];
    const float* g3  = (const float*)d_in[21];
    const float* b3  = (const float*)d_in[22];
    float* ws  = (float*)d_ws;
    float* out = (float*)d_out;

    // mats chunk capacity (floats available past W_MATS), constant across calls
    long long ws_floats = (long long)(ws_size / 4);
    long long mcap = ws_floats - (long long)W_MATS;
    if (mcap > 10485760LL) mcap = 10485760LL;          // largest single side (lote2)
    float* mats = ws + W_MATS;

    // ---- stage 1 (fused path: 1280 WGs, enough TLP) ----
    k_phi1<<<24576, 256, 0, stream>>>(x, ws + W_PHI1L, ws + W_PHI1C);
    k_mps1<<<1280, 256, 0, stream>>>(ws + W_PHI1L, ws + W_PHI1C, l1c, l1l, c1c, c1l,
                                     ws + W_LY, ws + W_CY);
    k_bn1<<<1280, 64, 0, stream>>>(ws + W_LY, ws + W_CY, g1, b1, gc1, bc1,
                                   ws + W_SCL, ws + W_SHL, ws + W_SCC, ws + W_SHC);
    k_labRB<<<160, 256, 0, stream>>>(l2l, c2l, l3l, c3l, ws);

    // ---- stage 2 ----
    k_phi2<<<10240, 256, 0, stream>>>(ws + W_LY, ws + W_CY, ws + W_SCL, ws + W_SHL,
                                      ws + W_SCC, ws + W_SHC, ws + W_PHI2L, ws + W_PHI2C);
    {
        int maxpL = (int)(mcap / (20 * 8192)); if (maxpL > 64) maxpL = 64;
        int maxpC = (int)(mcap / (16 * 8192)); if (maxpC > 64) maxpC = 64;
        run_side<20, 32>(ws + W_PHI2L, l2c, mats, ws + W_LR2L, ws + W_LO2, 64, 64, maxpL, stream);
        run_side<16, 40>(ws + W_PHI2C, c2c, mats, ws + W_LR2C, ws + W_CO2, 64, 64, maxpC, stream);
    }
    k_bn2<<<64, 64, 0, stream>>>(ws + W_LO2, ws + W_CO2, g2, b2, ws + W_SC2, ws + W_SH2);

    // ---- stage 3 ----
    k_phi3<<<1024, 256, 0, stream>>>(ws + W_LO2, ws + W_CO2, ws + W_SC2, ws + W_SH2,
                                     ws + W_PHI3L, ws + W_PHI3C);
    {
        int maxpL = (int)(mcap / (4 * 8192));  if (maxpL > 16) maxpL = 16;
        int maxpC = (int)(mcap / (32 * 8192)); if (maxpC > 16) maxpC = 16;
        run_side<4, 64>(ws + W_PHI3L, l3c, mats, ws + W_LR3L, ws + W_LO3, 16, 16, maxpL, stream);
        run_side<32, 8>(ws + W_PHI3C, c3c, mats, ws + W_LR3C, ws + W_CO3, 16, 16, maxpC, stream);
    }

    // ---- final ----
    k_bn3_phiF<<<1, 256, 0, stream>>>(ws + W_LO3, ws + W_CO3, g3, b3, ws + W_PHIF);
    k_mpsF_build<<<16, 256, 0, stream>>>(ws + W_PHIF, fc, ws + W_MF);
    k_mpsF_chain<<<1, 256, 0, stream>>>(ws + W_MF, fl, out);
}